// Round 14
// baseline (579.845 us; speedup 1.0000x reference)
//
#include <hip/hip_runtime.h>
#include <hip/hip_bf16.h>
#include <cstdint>
#include <cstddef>

typedef __attribute__((ext_vector_type(8))) short short8;
typedef __attribute__((ext_vector_type(4))) short short4_;
typedef __attribute__((ext_vector_type(4))) float floatx4;
typedef __attribute__((ext_vector_type(4))) unsigned short ushort4_;

#define MFMA16(a, b, c) __builtin_amdgcn_mfma_f32_16x16x32_bf16((a), (b), (c), 0, 0, 0)

__device__ __forceinline__ unsigned short f2bf(float f) {
  __hip_bfloat16 h = __float2bfloat16(f);
  return *reinterpret_cast<unsigned short*>(&h);
}

__device__ __forceinline__ void gl_lds16(const void* g, void* lds) {
  __builtin_amdgcn_global_load_lds(
      (const __attribute__((address_space(1))) void*)g,
      (__attribute__((address_space(3))) void*)lds, 16, 0, 0);
}

// ---------------------------------------------------------------- fused cast kernel
__global__ void cast5_f32_bf16(const float* __restrict__ x, const float* __restrict__ wq,
                               const float* __restrict__ wk, const float* __restrict__ wv,
                               const float* __restrict__ wo,
                               __hip_bfloat16* __restrict__ xb, __hip_bfloat16* __restrict__ wqb,
                               __hip_bfloat16* __restrict__ wkb, __hip_bfloat16* __restrict__ wvb,
                               __hip_bfloat16* __restrict__ wob) {
  const int bid = blockIdx.x;
  const float* src;
  __hip_bfloat16* dst;
  int base;
  if (bid < 16384)      { src = x;  dst = xb;  base = bid; }
  else if (bid < 20480) { src = wq; dst = wqb; base = bid - 16384; }
  else if (bid < 24576) { src = wk; dst = wkb; base = bid - 20480; }
  else if (bid < 28672) { src = wv; dst = wvb; base = bid - 24576; }
  else                  { src = wo; dst = wob; base = bid - 28672; }
  const int i = base * 1024 + threadIdx.x * 4;
  const float4 v = *reinterpret_cast<const float4*>(src + i);
  ushort4_ o = { f2bf(v.x), f2bf(v.y), f2bf(v.z), f2bf(v.w) };
  *reinterpret_cast<ushort4_*>(dst + i) = o;
}

// ---------------------------------------------------------------- GEMM: 256x256 tile, BK=32
// Phase-split schedule, 4-slot LDS ring, prefetch distance 3, counted vmcnt (never 0 in loop).
// Proven rounds 9-13 (~65 us/dispatch, 0 bank conflicts). UNCHANGED.
template <int MODE>
__global__ __launch_bounds__(512, 2)
void gemm256p(const __hip_bfloat16* __restrict__ Ap, const __hip_bfloat16* __restrict__ Bp,
              const float* __restrict__ bias, void* __restrict__ Cout,
              int M, int N, int K) {
  __shared__ __align__(16) __hip_bfloat16 SA[4][256 * 32];
  __shared__ __align__(16) __hip_bfloat16 SB[4][256 * 32];

  const int tid = threadIdx.x;
  const int wid = tid >> 6, lane = tid & 63;
  const int wr = wid >> 2, wc = wid & 3;
  const int g = lane >> 4, c16 = lane & 15;

  const int nbn = N >> 8;
  const int cpx = gridDim.x >> 3;
  const int swzb = (blockIdx.x & 7) * cpx + (blockIdx.x >> 3);
  const int bm = swzb / nbn, bn = swzb % nbn;

  const int srow = lane >> 2;
  const int slog = (lane & 3) ^ ((lane >> 3) & 3);
  const int swz = c16 * 32 + (g ^ ((c16 >> 1) & 3)) * 8;

  floatx4 acc[8][4] = {};
  short8 afA[4], afB[4], bf[4];

  auto stage_i = [&](int kt, int i) {
    const int kb = kt * 32;
    const int slot = kt & 3;
    const int rbase = i * 128 + wid * 16;
    gl_lds16(Ap + (size_t)(bm * 256 + rbase + srow) * K + kb + slog * 8,
             SA[slot] + rbase * 32);
    gl_lds16(Bp + (size_t)(bn * 256 + rbase + srow) * K + kb + slog * 8,
             SB[slot] + rbase * 32);
  };

  auto readA = [&](int slot, int half, short8* af) {
    const __hip_bfloat16* sa = SA[slot];
#pragma unroll
    for (int m = 0; m < 4; ++m)
      af[m] = *reinterpret_cast<const short8*>(sa + wr * 4096 + (half * 4 + m) * 512 + swz);
  };
  auto readB = [&](int slot) {
    const __hip_bfloat16* sb = SB[slot];
#pragma unroll
    for (int n = 0; n < 4; ++n)
      bf[n] = *reinterpret_cast<const short8*>(sb + wc * 2048 + n * 512 + swz);
  };
  auto mfma16 = [&](short8* af, int mh) {
    __builtin_amdgcn_s_setprio(1);
#pragma unroll
    for (int m = 0; m < 4; ++m)
#pragma unroll
      for (int n = 0; n < 4; ++n)
        acc[mh * 4 + m][n] = MFMA16(af[m], bf[n], acc[mh * 4 + m][n]);
    __builtin_amdgcn_s_setprio(0);
  };

  const int nkt = K >> 5;
  stage_i(0, 0); stage_i(0, 1);
  stage_i(1, 0); stage_i(1, 1);
  stage_i(2, 0); stage_i(2, 1);
  asm volatile("s_waitcnt vmcnt(8)" ::: "memory");   // drain tile 0
  __builtin_amdgcn_s_barrier();

  for (int kt = 0; kt < nkt - 3; ++kt) {
    const int s = kt & 3;
    readA(s, 0, afA);
    readB(s);
    stage_i(kt + 3, 0);
    asm volatile("" ::: "memory");
    __builtin_amdgcn_s_barrier();
    mfma16(afA, 0);
    asm volatile("" ::: "memory");
    __builtin_amdgcn_s_barrier();
    readA(s, 1, afB);
    stage_i(kt + 3, 1);
    asm volatile("s_waitcnt vmcnt(8)" ::: "memory");
    __builtin_amdgcn_s_barrier();
    mfma16(afB, 1);
    asm volatile("" ::: "memory");
    __builtin_amdgcn_s_barrier();
  }
#pragma unroll
  for (int t = 0; t < 3; ++t) {
    const int kt = nkt - 3 + t;
    const int s = kt & 3;
    readA(s, 0, afA);
    readB(s);
    asm volatile("" ::: "memory");
    __builtin_amdgcn_s_barrier();
    mfma16(afA, 0);
    asm volatile("" ::: "memory");
    __builtin_amdgcn_s_barrier();
    readA(s, 1, afB);
    if (t == 0) asm volatile("s_waitcnt vmcnt(4)" ::: "memory");
    else if (t == 1) asm volatile("s_waitcnt vmcnt(0)" ::: "memory");
    __builtin_amdgcn_s_barrier();
    mfma16(afB, 1);
    asm volatile("" ::: "memory");
    __builtin_amdgcn_s_barrier();
  }

#pragma unroll
  for (int n = 0; n < 4; ++n) {
    const int colg = bn * 256 + wc * 64 + n * 16 + c16;
    const float bv = bias[colg];
#pragma unroll
    for (int m = 0; m < 8; ++m) {
      const int rowg = bm * 256 + wr * 128 + m * 16 + g * 4;
      if (MODE == 0) {
        __hip_bfloat16* C = (__hip_bfloat16*)Cout;
#pragma unroll
        for (int j = 0; j < 4; ++j)
          C[(size_t)(rowg + j) * N + colg] = __float2bfloat16(acc[m][n][j] + bv);
      } else if (MODE == 1) {
        __hip_bfloat16* C = (__hip_bfloat16*)Cout;
        const int bb = rowg >> 11, t0 = rowg & 2047;
        ushort4_ pk = { f2bf(acc[m][n][0] + bv), f2bf(acc[m][n][1] + bv),
                        f2bf(acc[m][n][2] + bv), f2bf(acc[m][n][3] + bv) };
        *reinterpret_cast<ushort4_*>(C + ((size_t)bb * 2048 + colg) * 2048 + t0) = pk;
      } else {
        float* C = (float*)Cout;
#pragma unroll
        for (int j = 0; j < 4; ++j)
          C[(size_t)(rowg + j) * N + colg] = acc[m][n][j] + bv;
      }
    }
  }
}

// ---------------------------------------------------------------- flash attention v10 (causal)
// r11 structure (4 waves x 32 q, LB(256,2), magic-square mapping, K staged+XOR-swizzled,
// P via per-wave LDS) with V-STAGING DROPPED: vf read directly from Vt (XCD-L2 resident,
// 4 MB/XCD working set), 1-deep register ping-pong across dt to cover L2 latency.
__global__ __launch_bounds__(256, 2)
void attn_fwd10(const __hip_bfloat16* __restrict__ Q, const __hip_bfloat16* __restrict__ K,
                const __hip_bfloat16* __restrict__ Vt, __hip_bfloat16* __restrict__ ctx) {
  constexpr int T = 2048, C = 2048, D = 128;
  __shared__ __align__(16) __hip_bfloat16 Ks[64 * 128];    // 16 KB, slot^(row&7)
  __shared__ __align__(16) __hip_bfloat16 Pl[4][32][64];   //  8 KB/wave... 16 KB total
  // total LDS 32 KB

  const int tid = threadIdx.x;
  const int w = tid >> 6, lane = tid & 63;
  const int g = lane >> 4, c16 = lane & 15;

  // magic-square balanced mapping (round 11, proven)
  const int bid = blockIdx.x;
  const int x = bid & 7;
  const int i = bid >> 3;
  const int lo = i & 3, hi = i >> 5;
  const int bh = x * 8 + ((i >> 2) & 7);
  const int qb = (int)((0xF12C4A97865B3DE0ull >> (4 * (hi * 4 + lo))) & 15);
  const int b = bh >> 4, h = bh & 15;
  const int wq = qb * 128 + w * 32;

  const __hip_bfloat16* Qh = Q + (size_t)b * T * C + h * D;
  const __hip_bfloat16* Kh = K + (size_t)b * T * C + h * D;
  const __hip_bfloat16* Vh = Vt + (size_t)bh * D * T;

  short8 qf[2][4];
#pragma unroll
  for (int m = 0; m < 2; ++m)
#pragma unroll
    for (int kk = 0; kk < 4; ++kk)
      qf[m][kk] = *reinterpret_cast<const short8*>(Qh + (size_t)(wq + m * 16 + c16) * C + kk * 32 + g * 8);

  floatx4 acc[2][8] = {};
  float mrow[2] = {-INFINITY, -INFINITY};
  float lrow[2] = {0.f, 0.f};

  const float scale = 0.08838834764831845f;   // 1/sqrt(128)
  const int krow = tid >> 4;
  const int kslot = (tid & 15) ^ (krow & 7);
  const int kgcol = (tid & 15) * 8;

  short8 kr[4];
  auto gloadK = [&](int kb) {
#pragma unroll
    for (int p = 0; p < 4; ++p)
      kr[p] = *reinterpret_cast<const short8*>(Kh + (size_t)(kb + p * 16 + krow) * C + kgcol);
  };

  __hip_bfloat16 (*Pq)[64] = Pl[w];
  const int nkt = qb * 2 + 2;
  gloadK(0);

  for (int kt = 0; kt < nkt; ++kt) {
    const int kb = kt * 64;
    __syncthreads();                    // prior tile fully consumed
#pragma unroll
    for (int p = 0; p < 4; ++p)
      *reinterpret_cast<short8*>(&Ks[(p * 16 + krow) * 128 + kslot * 8]) = kr[p];
    __syncthreads();                    // staged K visible

    const bool hasnext = (kt + 1 < nkt);
    const bool part = (kb <= wq + 31);
    if (hasnext) gloadK(kb + 64);       // prefetch next K tile (regs)

    if (part) {
      floatx4 s[2][4] = {};
      __builtin_amdgcn_s_setprio(1);
#pragma unroll
      for (int n = 0; n < 4; ++n)
#pragma unroll
        for (int kk = 0; kk < 4; ++kk) {
          short8 kf = *reinterpret_cast<const short8*>(
              &Ks[(n * 16 + c16) * 128 + (((kk * 4 + g) ^ (c16 & 7)) * 8)]);
          s[0][n] = MFMA16(kf, qf[0][kk], s[0][n]);
          s[1][n] = MFMA16(kf, qf[1][kk], s[1][n]);
        }
      __builtin_amdgcn_s_setprio(0);
      const bool needmask = (kb + 63 > wq);
      float vmax[2];
#pragma unroll
      for (int m = 0; m < 2; ++m) {
        const int q = wq + m * 16 + c16;
        float vm = -INFINITY;
#pragma unroll
        for (int n = 0; n < 4; ++n)
#pragma unroll
          for (int j = 0; j < 4; ++j) {
            float a = s[m][n][j] * scale;
            if (needmask && (kb + n * 16 + g * 4 + j > q)) a = -INFINITY;
            s[m][n][j] = a;
            vm = fmaxf(vm, a);
          }
        vm = fmaxf(vm, __shfl_xor(vm, 16));
        vm = fmaxf(vm, __shfl_xor(vm, 32));
        vmax[m] = vm;
      }
      const float grow = fmaxf(vmax[0] - mrow[0], vmax[1] - mrow[1]);
      const bool nore = __all(grow <= 8.0f);
      short8 pb[2][2];
#pragma unroll
      for (int m = 0; m < 2; ++m) {
        const float mn = nore ? mrow[m] : fmaxf(mrow[m], vmax[m]);
        float rs = 0.f;
#pragma unroll
        for (int n = 0; n < 4; ++n) {
          float p0 = __expf(s[m][n][0] - mn), p1 = __expf(s[m][n][1] - mn);
          float p2 = __expf(s[m][n][2] - mn), p3 = __expf(s[m][n][3] - mn);
          rs += (p0 + p1) + (p2 + p3);
          ushort4_ pk = { f2bf(p0), f2bf(p1), f2bf(p2), f2bf(p3) };
          *reinterpret_cast<ushort4_*>(&Pq[m * 16 + c16][((4 * n + g) ^ c16) * 4]) = pk;
        }
        rs += __shfl_xor(rs, 16);
        rs += __shfl_xor(rs, 32);
        if (nore) {
          lrow[m] += rs;
        } else {
          const float sc = __expf(mrow[m] - mn);
          lrow[m] = lrow[m] * sc + rs;
          mrow[m] = mn;
#pragma unroll
          for (int dt = 0; dt < 8; ++dt)
#pragma unroll
            for (int j = 0; j < 4; ++j) acc[m][dt][j] *= sc;
        }
        // read this m's P fragments (DS in-order per wave)
#pragma unroll
        for (int ks = 0; ks < 2; ++ks) {
          short4_ lo2 = *reinterpret_cast<const short4_*>(&Pq[m * 16 + c16][((8 * ks + 2 * g) ^ c16) * 4]);
          short4_ hi2 = *reinterpret_cast<const short4_*>(&Pq[m * 16 + c16][((8 * ks + 2 * g + 1) ^ c16) * 4]);
          short8 r;
          r[0] = lo2[0]; r[1] = lo2[1]; r[2] = lo2[2]; r[3] = lo2[3];
          r[4] = hi2[0]; r[5] = hi2[1]; r[6] = hi2[2]; r[7] = hi2[3];
          pb[m][ks] = r;
        }
      }
      // ---- PV with V direct from L2 (Vt[(bh*128+d)][t]); 1-deep dt ping-pong
      short8 vf0[2], vf1[2];
#pragma unroll
      for (int ks = 0; ks < 2; ++ks)
        vf0[ks] = *reinterpret_cast<const short8*>(Vh + (size_t)(c16)*T + kb + ks * 32 + g * 8);
      __builtin_amdgcn_s_setprio(1);
#pragma unroll
      for (int dt = 0; dt < 8; ++dt) {
        short8* cur = (dt & 1) ? vf1 : vf0;
        short8* nx  = (dt & 1) ? vf0 : vf1;
        if (dt < 7) {
#pragma unroll
          for (int ks = 0; ks < 2; ++ks)
            nx[ks] = *reinterpret_cast<const short8*>(
                Vh + (size_t)((dt + 1) * 16 + c16) * T + kb + ks * 32 + g * 8);
        }
#pragma unroll
        for (int ks = 0; ks < 2; ++ks) {
          acc[0][dt] = MFMA16(cur[ks], pb[0][ks], acc[0][dt]);
          acc[1][dt] = MFMA16(cur[ks], pb[1][ks], acc[1][dt]);
        }
      }
      __builtin_amdgcn_s_setprio(0);
    }
  }

#pragma unroll
  for (int m = 0; m < 2; ++m) {
    const float inv = 1.0f / lrow[m];
    const size_t row = (size_t)b * T + wq + m * 16 + c16;
#pragma unroll
    for (int dt = 0; dt < 8; ++dt) {
      ushort4_ o = { f2bf(acc[m][dt][0] * inv), f2bf(acc[m][dt][1] * inv),
                     f2bf(acc[m][dt][2] * inv), f2bf(acc[m][dt][3] * inv) };
      *reinterpret_cast<ushort4_*>(ctx + row * C + h * D + dt * 16 + g * 4) = o;
    }
  }
}

// ---------------------------------------------------------------- launch
extern "C" void kernel_launch(void* const* d_in, const int* in_sizes, int n_in,
                              void* d_out, int out_size, void* d_ws, size_t ws_size,
                              hipStream_t stream) {
  const float* x  = (const float*)d_in[0];
  const float* Wq = (const float*)d_in[1];
  const float* bq = (const float*)d_in[2];
  const float* Wk = (const float*)d_in[3];
  const float* bk = (const float*)d_in[4];
  const float* Wv = (const float*)d_in[5];
  const float* bv = (const float*)d_in[6];
  const float* Wo = (const float*)d_in[7];
  const float* bo = (const float*)d_in[8];

  const int M = 8192, N = 2048, K = 2048;
  const size_t MB = 1u << 20;
  char* ws = (char*)d_ws;
  __hip_bfloat16* xb  = (__hip_bfloat16*)(ws);
  __hip_bfloat16* wqb = (__hip_bfloat16*)(ws + 32 * MB);
  __hip_bfloat16* wkb = (__hip_bfloat16*)(ws + 40 * MB);
  __hip_bfloat16* wvb = (__hip_bfloat16*)(ws + 48 * MB);
  __hip_bfloat16* wob = (__hip_bfloat16*)(ws + 56 * MB);
  __hip_bfloat16* Qb  = (__hip_bfloat16*)(ws + 64 * MB);
  __hip_bfloat16* Kb  = (__hip_bfloat16*)(ws + 96 * MB);
  __hip_bfloat16* Vtb = (__hip_bfloat16*)(ws + 128 * MB);
  if (ws_size < 160 * MB) return;

  cast5_f32_bf16<<<32768, 256, 0, stream>>>(x, Wq, Wk, Wv, Wo, xb, wqb, wkb, wvb, wob);

  const dim3 gg((M / 256) * (N / 256));
  gemm256p<0><<<gg, 512, 0, stream>>>(xb, wqb, bq, Qb, M, N, K);
  gemm256p<0><<<gg, 512, 0, stream>>>(xb, wkb, bk, Kb, M, N, K);
  gemm256p<1><<<gg, 512, 0, stream>>>(xb, wvb, bv, Vtb, M, N, K);

  attn_fwd10<<<64 * 16, 256, 0, stream>>>(Qb, Kb, Vtb, xb);

  gemm256p<2><<<gg, 512, 0, stream>>>(xb, wob, bo, d_out, M, N, K);
}

// Round 15
// 478.084 us; speedup vs baseline: 1.2129x; 1.2129x over previous
//
#include <hip/hip_runtime.h>
#include <hip/hip_bf16.h>
#include <cstdint>
#include <cstddef>

typedef __attribute__((ext_vector_type(8))) short short8;
typedef __attribute__((ext_vector_type(4))) short short4_;
typedef __attribute__((ext_vector_type(4))) float floatx4;
typedef __attribute__((ext_vector_type(4))) unsigned short ushort4_;

#define MFMA16(a, b, c) __builtin_amdgcn_mfma_f32_16x16x32_bf16((a), (b), (c), 0, 0, 0)

__device__ __forceinline__ unsigned short f2bf(float f) {
  __hip_bfloat16 h = __float2bfloat16(f);
  return *reinterpret_cast<unsigned short*>(&h);
}

__device__ __forceinline__ void gl_lds16(const void* g, void* lds) {
  __builtin_amdgcn_global_load_lds(
      (const __attribute__((address_space(1))) void*)g,
      (__attribute__((address_space(3))) void*)lds, 16, 0, 0);
}

// ---------------------------------------------------------------- fused cast kernel
__global__ void cast5_f32_bf16(const float* __restrict__ x, const float* __restrict__ wq,
                               const float* __restrict__ wk, const float* __restrict__ wv,
                               const float* __restrict__ wo,
                               __hip_bfloat16* __restrict__ xb, __hip_bfloat16* __restrict__ wqb,
                               __hip_bfloat16* __restrict__ wkb, __hip_bfloat16* __restrict__ wvb,
                               __hip_bfloat16* __restrict__ wob) {
  const int bid = blockIdx.x;
  const float* src;
  __hip_bfloat16* dst;
  int base;
  if (bid < 16384)      { src = x;  dst = xb;  base = bid; }
  else if (bid < 20480) { src = wq; dst = wqb; base = bid - 16384; }
  else if (bid < 24576) { src = wk; dst = wkb; base = bid - 20480; }
  else if (bid < 28672) { src = wv; dst = wvb; base = bid - 24576; }
  else                  { src = wo; dst = wob; base = bid - 28672; }
  const int i = base * 1024 + threadIdx.x * 4;
  const float4 v = *reinterpret_cast<const float4*>(src + i);
  ushort4_ o = { f2bf(v.x), f2bf(v.y), f2bf(v.z), f2bf(v.w) };
  *reinterpret_cast<ushort4_*>(dst + i) = o;
}

// ---------------------------------------------------------------- GEMM: 256x256 tile, BK=32
// Phase-split schedule, 4-slot LDS ring, prefetch distance 3, counted vmcnt (never 0 in loop).
// Proven rounds 9-14 (~65 us/dispatch, 0 bank conflicts). UNCHANGED.
template <int MODE>
__global__ __launch_bounds__(512, 2)
void gemm256p(const __hip_bfloat16* __restrict__ Ap, const __hip_bfloat16* __restrict__ Bp,
              const float* __restrict__ bias, void* __restrict__ Cout,
              int M, int N, int K) {
  __shared__ __align__(16) __hip_bfloat16 SA[4][256 * 32];
  __shared__ __align__(16) __hip_bfloat16 SB[4][256 * 32];

  const int tid = threadIdx.x;
  const int wid = tid >> 6, lane = tid & 63;
  const int wr = wid >> 2, wc = wid & 3;
  const int g = lane >> 4, c16 = lane & 15;

  const int nbn = N >> 8;
  const int cpx = gridDim.x >> 3;
  const int swzb = (blockIdx.x & 7) * cpx + (blockIdx.x >> 3);
  const int bm = swzb / nbn, bn = swzb % nbn;

  const int srow = lane >> 2;
  const int slog = (lane & 3) ^ ((lane >> 3) & 3);
  const int swz = c16 * 32 + (g ^ ((c16 >> 1) & 3)) * 8;

  floatx4 acc[8][4] = {};
  short8 afA[4], afB[4], bf[4];

  auto stage_i = [&](int kt, int i) {
    const int kb = kt * 32;
    const int slot = kt & 3;
    const int rbase = i * 128 + wid * 16;
    gl_lds16(Ap + (size_t)(bm * 256 + rbase + srow) * K + kb + slog * 8,
             SA[slot] + rbase * 32);
    gl_lds16(Bp + (size_t)(bn * 256 + rbase + srow) * K + kb + slog * 8,
             SB[slot] + rbase * 32);
  };

  auto readA = [&](int slot, int half, short8* af) {
    const __hip_bfloat16* sa = SA[slot];
#pragma unroll
    for (int m = 0; m < 4; ++m)
      af[m] = *reinterpret_cast<const short8*>(sa + wr * 4096 + (half * 4 + m) * 512 + swz);
  };
  auto readB = [&](int slot) {
    const __hip_bfloat16* sb = SB[slot];
#pragma unroll
    for (int n = 0; n < 4; ++n)
      bf[n] = *reinterpret_cast<const short8*>(sb + wc * 2048 + n * 512 + swz);
  };
  auto mfma16 = [&](short8* af, int mh) {
    __builtin_amdgcn_s_setprio(1);
#pragma unroll
    for (int m = 0; m < 4; ++m)
#pragma unroll
      for (int n = 0; n < 4; ++n)
        acc[mh * 4 + m][n] = MFMA16(af[m], bf[n], acc[mh * 4 + m][n]);
    __builtin_amdgcn_s_setprio(0);
  };

  const int nkt = K >> 5;
  stage_i(0, 0); stage_i(0, 1);
  stage_i(1, 0); stage_i(1, 1);
  stage_i(2, 0); stage_i(2, 1);
  asm volatile("s_waitcnt vmcnt(8)" ::: "memory");   // drain tile 0
  __builtin_amdgcn_s_barrier();

  for (int kt = 0; kt < nkt - 3; ++kt) {
    const int s = kt & 3;
    readA(s, 0, afA);
    readB(s);
    stage_i(kt + 3, 0);
    asm volatile("" ::: "memory");
    __builtin_amdgcn_s_barrier();
    mfma16(afA, 0);
    asm volatile("" ::: "memory");
    __builtin_amdgcn_s_barrier();
    readA(s, 1, afB);
    stage_i(kt + 3, 1);
    asm volatile("s_waitcnt vmcnt(8)" ::: "memory");
    __builtin_amdgcn_s_barrier();
    mfma16(afB, 1);
    asm volatile("" ::: "memory");
    __builtin_amdgcn_s_barrier();
  }
#pragma unroll
  for (int t = 0; t < 3; ++t) {
    const int kt = nkt - 3 + t;
    const int s = kt & 3;
    readA(s, 0, afA);
    readB(s);
    asm volatile("" ::: "memory");
    __builtin_amdgcn_s_barrier();
    mfma16(afA, 0);
    asm volatile("" ::: "memory");
    __builtin_amdgcn_s_barrier();
    readA(s, 1, afB);
    if (t == 0) asm volatile("s_waitcnt vmcnt(4)" ::: "memory");
    else if (t == 1) asm volatile("s_waitcnt vmcnt(0)" ::: "memory");
    __builtin_amdgcn_s_barrier();
    mfma16(afB, 1);
    asm volatile("" ::: "memory");
    __builtin_amdgcn_s_barrier();
  }

#pragma unroll
  for (int n = 0; n < 4; ++n) {
    const int colg = bn * 256 + wc * 64 + n * 16 + c16;
    const float bv = bias[colg];
#pragma unroll
    for (int m = 0; m < 8; ++m) {
      const int rowg = bm * 256 + wr * 128 + m * 16 + g * 4;
      if (MODE == 0) {
        __hip_bfloat16* C = (__hip_bfloat16*)Cout;
#pragma unroll
        for (int j = 0; j < 4; ++j)
          C[(size_t)(rowg + j) * N + colg] = __float2bfloat16(acc[m][n][j] + bv);
      } else if (MODE == 1) {
        __hip_bfloat16* C = (__hip_bfloat16*)Cout;
        const int bb = rowg >> 11, t0 = rowg & 2047;
        ushort4_ pk = { f2bf(acc[m][n][0] + bv), f2bf(acc[m][n][1] + bv),
                        f2bf(acc[m][n][2] + bv), f2bf(acc[m][n][3] + bv) };
        *reinterpret_cast<ushort4_*>(C + ((size_t)bb * 2048 + colg) * 2048 + t0) = pk;
      } else {
        float* C = (float*)Cout;
#pragma unroll
        for (int j = 0; j < 4; ++j)
          C[(size_t)(rowg + j) * N + colg] = acc[m][n][j] + bv;
      }
    }
  }
}

// ---------------------------------------------------------------- flash attention v11 (causal)
// r11 structure (4 waves x 32 q, LB(256,2), magic-square map, swapped-operand softmax,
// __expf, defer-max, P per-wave LDS) with K/V staging converted to global_load_lds DMA
// into a DOUBLE BUFFER, ONE barrier per tile:
//   tile kt: issue 8 DMA ops (buf nxt) -> compute from buf[cur] -> __syncthreads()
//            (implicit vmcnt(0) retires this wave's DMAs; barrier publishes buf nxt).
// Swizzle both-sides rule: LDS dest linear (chunk base + lane*16); global SOURCE col
// pre-swizzled by (slot ^ (row&7)) — the same involution the reads use (K: row&7=c16&7,
// V: row&7 = lane>>3). LDS image identical to the r11 proven layout.
__global__ __launch_bounds__(256, 2)
void attn_fwd11(const __hip_bfloat16* __restrict__ Q, const __hip_bfloat16* __restrict__ K,
                const __hip_bfloat16* __restrict__ Vt, __hip_bfloat16* __restrict__ ctx) {
  constexpr int T = 2048, C = 2048, D = 128;
  __shared__ __align__(16) __hip_bfloat16 Ks[2][64 * 128];   // 2 x 16 KB
  __shared__ __align__(16) __hip_bfloat16 Vs[2][128 * 64];   // 2 x 16 KB
  __shared__ __align__(16) __hip_bfloat16 Pl[4][32][64];     // 16 KB
  // total 81920... (Pl is 4*32*64*2 = 16 KB) -> 32+32+16 = 80 KB -> 2 blocks/CU exactly

  const int tid = threadIdx.x;
  const int w = tid >> 6, lane = tid & 63;
  const int g = lane >> 4, c16 = lane & 15;

  // magic-square balanced mapping (round 11, proven)
  const int bid = blockIdx.x;
  const int x = bid & 7;
  const int i = bid >> 3;
  const int lo = i & 3, hi = i >> 5;
  const int bh = x * 8 + ((i >> 2) & 7);
  const int qb = (int)((0xF12C4A97865B3DE0ull >> (4 * (hi * 4 + lo))) & 15);
  const int b = bh >> 4, h = bh & 15;
  const int wq = qb * 128 + w * 32;

  const __hip_bfloat16* Qh = Q + (size_t)b * T * C + h * D;
  const __hip_bfloat16* Kh = K + (size_t)b * T * C + h * D;
  const __hip_bfloat16* Vh = Vt + (size_t)bh * D * T;

  short8 qf[2][4];
#pragma unroll
  for (int m = 0; m < 2; ++m)
#pragma unroll
    for (int kk = 0; kk < 4; ++kk)
      qf[m][kk] = *reinterpret_cast<const short8*>(Qh + (size_t)(wq + m * 16 + c16) * C + kk * 32 + g * 8);

  floatx4 acc[2][8] = {};
  float mrow[2] = {-INFINITY, -INFINITY};
  float lrow[2] = {0.f, 0.f};

  const float scale = 0.08838834764831845f;   // 1/sqrt(128)
  const int kl4 = lane >> 4;   // K: row within 4-row chunk
  const int ks4 = lane & 15;   // K: 16B slot
  const int vl8 = lane >> 3;   // V: row within 8-row chunk
  const int vs8 = lane & 7;    // V: 16B slot

  // per tile, per wave: 4 K-chunk DMAs (1 KB each) + 4 V-chunk DMAs
  auto issueKV = [&](int kb, int buf) {
#pragma unroll
    for (int ii = 0; ii < 4; ++ii) {
      const int ck = w + ii * 4;                 // chunk 0..15 (4 rows each)
      const int krw = ck * 4 + kl4;              // tile row 0..63
      gl_lds16(Kh + (size_t)(kb + krw) * C + ((ks4 ^ (krw & 7)) * 8),
               &Ks[buf][ck * 512]);
      const int cv = w + ii * 4;                 // chunk 0..15 (8 rows each)
      const int vrw = cv * 8 + vl8;              // tile row (d) 0..127
      gl_lds16(Vh + (size_t)vrw * T + kb + ((vs8 ^ vl8) * 8),
               &Vs[buf][cv * 512]);
    }
  };

  __hip_bfloat16 (*Pq)[64] = Pl[w];
  const int nkt = qb * 2 + 2;

  issueKV(0, 0);
  __syncthreads();                  // vmcnt(0) drains this wave's DMAs; buf0 published

  for (int kt = 0; kt < nkt; ++kt) {
    const int kb = kt * 64;
    const int cur = kt & 1;
    const bool hasnext = (kt + 1 < nkt);
    const bool part = (kb <= wq + 31);

    if (hasnext) issueKV(kb + 64, cur ^ 1);     // async DMA, in flight across compute

    if (part) {
      floatx4 s[2][4] = {};
      __builtin_amdgcn_s_setprio(1);
#pragma unroll
      for (int n = 0; n < 4; ++n)
#pragma unroll
        for (int kk = 0; kk < 4; ++kk) {
          short8 kf = *reinterpret_cast<const short8*>(
              &Ks[cur][(n * 16 + c16) * 128 + (((kk * 4 + g) ^ (c16 & 7)) * 8)]);
          s[0][n] = MFMA16(kf, qf[0][kk], s[0][n]);
          s[1][n] = MFMA16(kf, qf[1][kk], s[1][n]);
        }
      __builtin_amdgcn_s_setprio(0);
      const bool needmask = (kb + 63 > wq);
      float vmax[2];
#pragma unroll
      for (int m = 0; m < 2; ++m) {
        const int q = wq + m * 16 + c16;
        float vm = -INFINITY;
#pragma unroll
        for (int n = 0; n < 4; ++n)
#pragma unroll
          for (int j = 0; j < 4; ++j) {
            float a = s[m][n][j] * scale;
            if (needmask && (kb + n * 16 + g * 4 + j > q)) a = -INFINITY;
            s[m][n][j] = a;
            vm = fmaxf(vm, a);
          }
        vm = fmaxf(vm, __shfl_xor(vm, 16));
        vm = fmaxf(vm, __shfl_xor(vm, 32));
        vmax[m] = vm;
      }
      const float grow = fmaxf(vmax[0] - mrow[0], vmax[1] - mrow[1]);
      const bool nore = __all(grow <= 8.0f);
      short8 pb[2][2];
#pragma unroll
      for (int m = 0; m < 2; ++m) {
        const float mn = nore ? mrow[m] : fmaxf(mrow[m], vmax[m]);
        float rs = 0.f;
#pragma unroll
        for (int n = 0; n < 4; ++n) {
          float p0 = __expf(s[m][n][0] - mn), p1 = __expf(s[m][n][1] - mn);
          float p2 = __expf(s[m][n][2] - mn), p3 = __expf(s[m][n][3] - mn);
          rs += (p0 + p1) + (p2 + p3);
          ushort4_ pk = { f2bf(p0), f2bf(p1), f2bf(p2), f2bf(p3) };
          *reinterpret_cast<ushort4_*>(&Pq[m * 16 + c16][((4 * n + g) ^ c16) * 4]) = pk;
        }
        rs += __shfl_xor(rs, 16);
        rs += __shfl_xor(rs, 32);
        if (nore) {
          lrow[m] += rs;
        } else {
          const float sc = __expf(mrow[m] - mn);
          lrow[m] = lrow[m] * sc + rs;
          mrow[m] = mn;
#pragma unroll
          for (int dt = 0; dt < 8; ++dt)
#pragma unroll
            for (int j = 0; j < 4; ++j) acc[m][dt][j] *= sc;
        }
        // read this m's P fragments (DS in-order per wave)
#pragma unroll
        for (int ks = 0; ks < 2; ++ks) {
          short4_ lo2 = *reinterpret_cast<const short4_*>(&Pq[m * 16 + c16][((8 * ks + 2 * g) ^ c16) * 4]);
          short4_ hi2 = *reinterpret_cast<const short4_*>(&Pq[m * 16 + c16][((8 * ks + 2 * g + 1) ^ c16) * 4]);
          short8 r;
          r[0] = lo2[0]; r[1] = lo2[1]; r[2] = lo2[2]; r[3] = lo2[3];
          r[4] = hi2[0]; r[5] = hi2[1]; r[6] = hi2[2]; r[7] = hi2[3];
          pb[m][ks] = r;
        }
      }
      __builtin_amdgcn_s_setprio(1);
#pragma unroll
      for (int dt = 0; dt < 8; ++dt)
#pragma unroll
        for (int ks = 0; ks < 2; ++ks) {
          const int pslot = ((ks * 4 + g) ^ (c16 & 7)) * 8;
          short8 vf = *reinterpret_cast<const short8*>(&Vs[cur][(dt * 16 + c16) * 64 + pslot]);
          acc[0][dt] = MFMA16(vf, pb[0][ks], acc[0][dt]);
          acc[1][dt] = MFMA16(vf, pb[1][ks], acc[1][dt]);
        }
      __builtin_amdgcn_s_setprio(0);
    }

    __syncthreads();   // vmcnt(0): this wave's DMAs (issued pre-compute) retired;
                       // barrier publishes buf[nxt] and closes reads of buf[cur]
  }

#pragma unroll
  for (int m = 0; m < 2; ++m) {
    const float inv = 1.0f / lrow[m];
    const size_t row = (size_t)b * T + wq + m * 16 + c16;
#pragma unroll
    for (int dt = 0; dt < 8; ++dt) {
      ushort4_ o = { f2bf(acc[m][dt][0] * inv), f2bf(acc[m][dt][1] * inv),
                     f2bf(acc[m][dt][2] * inv), f2bf(acc[m][dt][3] * inv) };
      *reinterpret_cast<ushort4_*>(ctx + row * C + h * D + dt * 16 + g * 4) = o;
    }
  }
}

// ---------------------------------------------------------------- launch
extern "C" void kernel_launch(void* const* d_in, const int* in_sizes, int n_in,
                              void* d_out, int out_size, void* d_ws, size_t ws_size,
                              hipStream_t stream) {
  const float* x  = (const float*)d_in[0];
  const float* Wq = (const float*)d_in[1];
  const float* bq = (const float*)d_in[2];
  const float* Wk = (const float*)d_in[3];
  const float* bk = (const float*)d_in[4];
  const float* Wv = (const float*)d_in[5];
  const float* bv = (const float*)d_in[6];
  const float* Wo = (const float*)d_in[7];
  const float* bo = (const float*)d_in[8];

  const int M = 8192, N = 2048, K = 2048;
  const size_t MB = 1u << 20;
  char* ws = (char*)d_ws;
  __hip_bfloat16* xb  = (__hip_bfloat16*)(ws);
  __hip_bfloat16* wqb = (__hip_bfloat16*)(ws + 32 * MB);
  __hip_bfloat16* wkb = (__hip_bfloat16*)(ws + 40 * MB);
  __hip_bfloat16* wvb = (__hip_bfloat16*)(ws + 48 * MB);
  __hip_bfloat16* wob = (__hip_bfloat16*)(ws + 56 * MB);
  __hip_bfloat16* Qb  = (__hip_bfloat16*)(ws + 64 * MB);
  __hip_bfloat16* Kb  = (__hip_bfloat16*)(ws + 96 * MB);
  __hip_bfloat16* Vtb = (__hip_bfloat16*)(ws + 128 * MB);
  if (ws_size < 160 * MB) return;

  cast5_f32_bf16<<<32768, 256, 0, stream>>>(x, Wq, Wk, Wv, Wo, xb, wqb, wkb, wvb, wob);

  const dim3 gg((M / 256) * (N / 256));
  gemm256p<0><<<gg, 512, 0, stream>>>(xb, wqb, bq, Qb, M, N, K);
  gemm256p<0><<<gg, 512, 0, stream>>>(xb, wkb, bk, Kb, M, N, K);
  gemm256p<1><<<gg, 512, 0, stream>>>(xb, wvb, bv, Vtb, M, N, K);

  attn_fwd11<<<64 * 16, 256, 0, stream>>>(Qb, Kb, Vtb, xb);

  gemm256p<2><<<gg, 512, 0, stream>>>(xb, wob, bo, d_out, M, N, K);
}

// Round 16
// 446.666 us; speedup vs baseline: 1.2982x; 1.0703x over previous
//
#include <hip/hip_runtime.h>
#include <hip/hip_bf16.h>
#include <cstdint>
#include <cstddef>

typedef __attribute__((ext_vector_type(8))) short short8;
typedef __attribute__((ext_vector_type(4))) short short4_;
typedef __attribute__((ext_vector_type(4))) float floatx4;
typedef __attribute__((ext_vector_type(4))) unsigned short ushort4_;

#define MFMA16(a, b, c) __builtin_amdgcn_mfma_f32_16x16x32_bf16((a), (b), (c), 0, 0, 0)

__device__ __forceinline__ unsigned short f2bf(float f) {
  __hip_bfloat16 h = __float2bfloat16(f);
  return *reinterpret_cast<unsigned short*>(&h);
}

__device__ __forceinline__ float exp2_fast(float x) {   // bare v_exp_f32 (exp2)
  float r;
  asm("v_exp_f32 %0, %1" : "=v"(r) : "v"(x));
  return r;
}

__device__ __forceinline__ void gl_lds16(const void* g, void* lds) {
  __builtin_amdgcn_global_load_lds(
      (const __attribute__((address_space(1))) void*)g,
      (__attribute__((address_space(3))) void*)lds, 16, 0, 0);
}

// ---------------------------------------------------------------- fused cast kernel
__global__ void cast5_f32_bf16(const float* __restrict__ x, const float* __restrict__ wq,
                               const float* __restrict__ wk, const float* __restrict__ wv,
                               const float* __restrict__ wo,
                               __hip_bfloat16* __restrict__ xb, __hip_bfloat16* __restrict__ wqb,
                               __hip_bfloat16* __restrict__ wkb, __hip_bfloat16* __restrict__ wvb,
                               __hip_bfloat16* __restrict__ wob) {
  const int bid = blockIdx.x;
  const float* src;
  __hip_bfloat16* dst;
  int base;
  if (bid < 16384)      { src = x;  dst = xb;  base = bid; }
  else if (bid < 20480) { src = wq; dst = wqb; base = bid - 16384; }
  else if (bid < 24576) { src = wk; dst = wkb; base = bid - 20480; }
  else if (bid < 28672) { src = wv; dst = wvb; base = bid - 24576; }
  else                  { src = wo; dst = wob; base = bid - 28672; }
  const int i = base * 1024 + threadIdx.x * 4;
  const float4 v = *reinterpret_cast<const float4*>(src + i);
  ushort4_ o = { f2bf(v.x), f2bf(v.y), f2bf(v.z), f2bf(v.w) };
  *reinterpret_cast<ushort4_*>(dst + i) = o;
}

// ---------------------------------------------------------------- GEMM: 256x256 tile, BK=32
// Phase-split schedule, 4-slot LDS ring, prefetch distance 3, counted vmcnt (never 0 in loop).
// Proven rounds 9-15 (~65 us/dispatch, 0 bank conflicts). UNCHANGED.
template <int MODE>
__global__ __launch_bounds__(512, 2)
void gemm256p(const __hip_bfloat16* __restrict__ Ap, const __hip_bfloat16* __restrict__ Bp,
              const float* __restrict__ bias, void* __restrict__ Cout,
              int M, int N, int K) {
  __shared__ __align__(16) __hip_bfloat16 SA[4][256 * 32];
  __shared__ __align__(16) __hip_bfloat16 SB[4][256 * 32];

  const int tid = threadIdx.x;
  const int wid = tid >> 6, lane = tid & 63;
  const int wr = wid >> 2, wc = wid & 3;
  const int g = lane >> 4, c16 = lane & 15;

  const int nbn = N >> 8;
  const int cpx = gridDim.x >> 3;
  const int swzb = (blockIdx.x & 7) * cpx + (blockIdx.x >> 3);
  const int bm = swzb / nbn, bn = swzb % nbn;

  const int srow = lane >> 2;
  const int slog = (lane & 3) ^ ((lane >> 3) & 3);
  const int swz = c16 * 32 + (g ^ ((c16 >> 1) & 3)) * 8;

  floatx4 acc[8][4] = {};
  short8 afA[4], afB[4], bf[4];

  auto stage_i = [&](int kt, int i) {
    const int kb = kt * 32;
    const int slot = kt & 3;
    const int rbase = i * 128 + wid * 16;
    gl_lds16(Ap + (size_t)(bm * 256 + rbase + srow) * K + kb + slog * 8,
             SA[slot] + rbase * 32);
    gl_lds16(Bp + (size_t)(bn * 256 + rbase + srow) * K + kb + slog * 8,
             SB[slot] + rbase * 32);
  };

  auto readA = [&](int slot, int half, short8* af) {
    const __hip_bfloat16* sa = SA[slot];
#pragma unroll
    for (int m = 0; m < 4; ++m)
      af[m] = *reinterpret_cast<const short8*>(sa + wr * 4096 + (half * 4 + m) * 512 + swz);
  };
  auto readB = [&](int slot) {
    const __hip_bfloat16* sb = SB[slot];
#pragma unroll
    for (int n = 0; n < 4; ++n)
      bf[n] = *reinterpret_cast<const short8*>(sb + wc * 2048 + n * 512 + swz);
  };
  auto mfma16 = [&](short8* af, int mh) {
    __builtin_amdgcn_s_setprio(1);
#pragma unroll
    for (int m = 0; m < 4; ++m)
#pragma unroll
      for (int n = 0; n < 4; ++n)
        acc[mh * 4 + m][n] = MFMA16(af[m], bf[n], acc[mh * 4 + m][n]);
    __builtin_amdgcn_s_setprio(0);
  };

  const int nkt = K >> 5;
  stage_i(0, 0); stage_i(0, 1);
  stage_i(1, 0); stage_i(1, 1);
  stage_i(2, 0); stage_i(2, 1);
  asm volatile("s_waitcnt vmcnt(8)" ::: "memory");   // drain tile 0
  __builtin_amdgcn_s_barrier();

  for (int kt = 0; kt < nkt - 3; ++kt) {
    const int s = kt & 3;
    readA(s, 0, afA);
    readB(s);
    stage_i(kt + 3, 0);
    asm volatile("" ::: "memory");
    __builtin_amdgcn_s_barrier();
    mfma16(afA, 0);
    asm volatile("" ::: "memory");
    __builtin_amdgcn_s_barrier();
    readA(s, 1, afB);
    stage_i(kt + 3, 1);
    asm volatile("s_waitcnt vmcnt(8)" ::: "memory");
    __builtin_amdgcn_s_barrier();
    mfma16(afB, 1);
    asm volatile("" ::: "memory");
    __builtin_amdgcn_s_barrier();
  }
#pragma unroll
  for (int t = 0; t < 3; ++t) {
    const int kt = nkt - 3 + t;
    const int s = kt & 3;
    readA(s, 0, afA);
    readB(s);
    asm volatile("" ::: "memory");
    __builtin_amdgcn_s_barrier();
    mfma16(afA, 0);
    asm volatile("" ::: "memory");
    __builtin_amdgcn_s_barrier();
    readA(s, 1, afB);
    if (t == 0) asm volatile("s_waitcnt vmcnt(4)" ::: "memory");
    else if (t == 1) asm volatile("s_waitcnt vmcnt(0)" ::: "memory");
    __builtin_amdgcn_s_barrier();
    mfma16(afB, 1);
    asm volatile("" ::: "memory");
    __builtin_amdgcn_s_barrier();
  }

#pragma unroll
  for (int n = 0; n < 4; ++n) {
    const int colg = bn * 256 + wc * 64 + n * 16 + c16;
    const float bv = bias[colg];
#pragma unroll
    for (int m = 0; m < 8; ++m) {
      const int rowg = bm * 256 + wr * 128 + m * 16 + g * 4;
      if (MODE == 0) {
        __hip_bfloat16* C = (__hip_bfloat16*)Cout;
#pragma unroll
        for (int j = 0; j < 4; ++j)
          C[(size_t)(rowg + j) * N + colg] = __float2bfloat16(acc[m][n][j] + bv);
      } else if (MODE == 1) {
        __hip_bfloat16* C = (__hip_bfloat16*)Cout;
        const int bb = rowg >> 11, t0 = rowg & 2047;
        ushort4_ pk = { f2bf(acc[m][n][0] + bv), f2bf(acc[m][n][1] + bv),
                        f2bf(acc[m][n][2] + bv), f2bf(acc[m][n][3] + bv) };
        *reinterpret_cast<ushort4_*>(C + ((size_t)bb * 2048 + colg) * 2048 + t0) = pk;
      } else {
        float* C = (float*)Cout;
#pragma unroll
        for (int j = 0; j < 4; ++j)
          C[(size_t)(rowg + j) * N + colg] = acc[m][n][j] + bv;
      }
    }
  }
}

// ---------------------------------------------------------------- flash attention v12 (causal)
// = round-11 attn_fwd7 (167 us proven: single-buffer K/V, magic-square map, XOR LDS,
//   Pl[16x64] m-sequenced, LB(256,2)) + three VALU cuts:
//   (1) Q pre-scaled by 1/sqrt(D)*log2(e) at load -> no per-tile scale mul, exp2 domain
//   (2) bare v_exp_f32 via asm (no libm, no hidden mul-by-log2e)
//   (3) wave-uniform mask-path split (cmp+cndmask only on the 1-2 diagonal tiles)
__global__ __launch_bounds__(256, 2)
void attn_fwd12(const __hip_bfloat16* __restrict__ Q, const __hip_bfloat16* __restrict__ K,
                const __hip_bfloat16* __restrict__ Vt, __hip_bfloat16* __restrict__ ctx) {
  constexpr int T = 2048, C = 2048, D = 128;
  __shared__ __align__(16) __hip_bfloat16 Ks[64 * 128];    // 16 KB, slot^(row&7)
  __shared__ __align__(16) __hip_bfloat16 Vs[128 * 64];    // 16 KB, slot^(row&7)
  __shared__ __align__(16) __hip_bfloat16 Pl[4][16 * 64];  //  8 KB, slot^c16, m-sequenced

  const int tid = threadIdx.x;
  const int w = tid >> 6, lane = tid & 63;
  const int g = lane >> 4, c16 = lane & 15;

  // magic-square balanced mapping (round 11, proven)
  const int bid = blockIdx.x;
  const int x = bid & 7;
  const int i = bid >> 3;
  const int lo = i & 3, hi = i >> 5;
  const int bh = x * 8 + ((i >> 2) & 7);
  const int qb = (int)((0xF12C4A97865B3DE0ull >> (4 * (hi * 4 + lo))) & 15);
  const int b = bh >> 4, h = bh & 15;
  const int wq = qb * 128 + w * 32;

  const __hip_bfloat16* Qh = Q + (size_t)b * T * C + h * D;
  const __hip_bfloat16* Kh = K + (size_t)b * T * C + h * D;
  const __hip_bfloat16* Vh = Vt + (size_t)bh * D * T;

  const float scale2 = 0.12751744f;   // (1/sqrt(128)) * log2(e): exp2-domain softmax

  // Q fragments, pre-scaled (one-time cost)
  short8 qf[2][4];
#pragma unroll
  for (int m = 0; m < 2; ++m)
#pragma unroll
    for (int kk = 0; kk < 4; ++kk) {
      short8 v = *reinterpret_cast<const short8*>(Qh + (size_t)(wq + m * 16 + c16) * C + kk * 32 + g * 8);
      short8 r;
#pragma unroll
      for (int e = 0; e < 8; ++e) {
        unsigned short u = (unsigned short)v[e];
        __hip_bfloat16 bh16 = *reinterpret_cast<__hip_bfloat16*>(&u);
        r[e] = (short)f2bf(__bfloat162float(bh16) * scale2);
      }
      qf[m][kk] = r;
    }

  floatx4 acc[2][8] = {};
  float mrow[2] = {-INFINITY, -INFINITY};
  float lrow[2] = {0.f, 0.f};

  const int krow = tid >> 4;
  const int kslot = (tid & 15) ^ (krow & 7);
  const int kgcol = (tid & 15) * 8;
  const int vrow = tid >> 3;
  const int vslot = (tid & 7) ^ (vrow & 7);
  const int vgcol = (tid & 7) * 8;

  short8 kr[4], vr[4];
  auto gloadK = [&](int kb) {
#pragma unroll
    for (int p = 0; p < 4; ++p)
      kr[p] = *reinterpret_cast<const short8*>(Kh + (size_t)(kb + p * 16 + krow) * C + kgcol);
  };
  auto gloadV = [&](int kb) {
#pragma unroll
    for (int p = 0; p < 4; ++p)
      vr[p] = *reinterpret_cast<const short8*>(Vh + (size_t)(p * 32 + vrow) * T + kb + vgcol);
  };

  __hip_bfloat16* Pq = Pl[w];
  const int nkt = qb * 2 + 2;
  gloadK(0);
  gloadV(0);

  for (int kt = 0; kt < nkt; ++kt) {
    const int kb = kt * 64;
    __syncthreads();
#pragma unroll
    for (int p = 0; p < 4; ++p)
      *reinterpret_cast<short8*>(&Ks[(p * 16 + krow) * 128 + kslot * 8]) = kr[p];
#pragma unroll
    for (int p = 0; p < 4; ++p)
      *reinterpret_cast<short8*>(&Vs[(p * 32 + vrow) * 64 + vslot * 8]) = vr[p];
    __syncthreads();

    const bool hasnext = (kt + 1 < nkt);
    const bool part = (kb <= wq + 31);
    if (hasnext) gloadK(kb + 64);

    short8 pb[2][2];
    if (part) {
      floatx4 s[2][4] = {};
      __builtin_amdgcn_s_setprio(1);
#pragma unroll
      for (int n = 0; n < 4; ++n)
#pragma unroll
        for (int kk = 0; kk < 4; ++kk) {
          short8 kf = *reinterpret_cast<const short8*>(
              &Ks[(n * 16 + c16) * 128 + (((kk * 4 + g) ^ (c16 & 7)) * 8)]);
          s[0][n] = MFMA16(kf, qf[0][kk], s[0][n]);
          s[1][n] = MFMA16(kf, qf[1][kk], s[1][n]);
        }
      __builtin_amdgcn_s_setprio(0);

      // ---- row max; mask only on diagonal tiles (wave-uniform branch)
      const bool needmask = (kb + 63 > wq);
      float vmax[2];
      if (needmask) {
#pragma unroll
        for (int m = 0; m < 2; ++m) {
          const int q = wq + m * 16 + c16;
          float vm = -INFINITY;
#pragma unroll
          for (int n = 0; n < 4; ++n)
#pragma unroll
            for (int j = 0; j < 4; ++j) {
              float a = s[m][n][j];
              if (kb + n * 16 + g * 4 + j > q) a = -INFINITY;
              s[m][n][j] = a;
              vm = fmaxf(vm, a);
            }
          vmax[m] = vm;
        }
      } else {
#pragma unroll
        for (int m = 0; m < 2; ++m) {
          float v0 = fmaxf(fmaxf(s[m][0][0], s[m][0][1]), fmaxf(s[m][0][2], s[m][0][3]));
          float v1 = fmaxf(fmaxf(s[m][1][0], s[m][1][1]), fmaxf(s[m][1][2], s[m][1][3]));
          float v2 = fmaxf(fmaxf(s[m][2][0], s[m][2][1]), fmaxf(s[m][2][2], s[m][2][3]));
          float v3 = fmaxf(fmaxf(s[m][3][0], s[m][3][1]), fmaxf(s[m][3][2], s[m][3][3]));
          vmax[m] = fmaxf(fmaxf(v0, v1), fmaxf(v2, v3));
        }
      }
#pragma unroll
      for (int m = 0; m < 2; ++m) {
        vmax[m] = fmaxf(vmax[m], __shfl_xor(vmax[m], 16));
        vmax[m] = fmaxf(vmax[m], __shfl_xor(vmax[m], 32));
      }
      const float grow = fmaxf(vmax[0] - mrow[0], vmax[1] - mrow[1]);
      const bool nore = __all(grow <= 8.0f);   // P bounded by 2^8 when deferred
#pragma unroll
      for (int m = 0; m < 2; ++m) {
        const float mn = nore ? mrow[m] : fmaxf(mrow[m], vmax[m]);
        float rs = 0.f;
#pragma unroll
        for (int n = 0; n < 4; ++n) {
          float p0 = exp2_fast(s[m][n][0] - mn), p1 = exp2_fast(s[m][n][1] - mn);
          float p2 = exp2_fast(s[m][n][2] - mn), p3 = exp2_fast(s[m][n][3] - mn);
          rs += (p0 + p1) + (p2 + p3);
          ushort4_ pk = { f2bf(p0), f2bf(p1), f2bf(p2), f2bf(p3) };
          *reinterpret_cast<ushort4_*>(&Pq[c16 * 64 + (((4 * n + g) ^ c16) * 4)]) = pk;
        }
        rs += __shfl_xor(rs, 16);
        rs += __shfl_xor(rs, 32);
        if (nore) {
          lrow[m] += rs;
        } else {
          const float sc = exp2_fast(mrow[m] - mn);
          lrow[m] = lrow[m] * sc + rs;
          mrow[m] = mn;
#pragma unroll
          for (int dt = 0; dt < 8; ++dt)
#pragma unroll
            for (int j = 0; j < 4; ++j) acc[m][dt][j] *= sc;
        }
        // read this m's P fragments before m+1 overwrites (DS in-order per wave)
#pragma unroll
        for (int ks = 0; ks < 2; ++ks) {
          short4_ lo2 = *reinterpret_cast<const short4_*>(&Pq[c16 * 64 + (((8 * ks + 2 * g) ^ c16) * 4)]);
          short4_ hi2 = *reinterpret_cast<const short4_*>(&Pq[c16 * 64 + (((8 * ks + 2 * g + 1) ^ c16) * 4)]);
          short8 r;
          r[0] = lo2[0]; r[1] = lo2[1]; r[2] = lo2[2]; r[3] = lo2[3];
          r[4] = hi2[0]; r[5] = hi2[1]; r[6] = hi2[2]; r[7] = hi2[3];
          pb[m][ks] = r;
        }
      }
    }
    if (hasnext) gloadV(kb + 64);
    if (part) {
      __builtin_amdgcn_s_setprio(1);
#pragma unroll
      for (int dt = 0; dt < 8; ++dt)
#pragma unroll
        for (int ks = 0; ks < 2; ++ks) {
          const int pslot = ((ks * 4 + g) ^ (c16 & 7)) * 8;
          short8 vf = *reinterpret_cast<const short8*>(&Vs[(dt * 16 + c16) * 64 + pslot]);
          acc[0][dt] = MFMA16(vf, pb[0][ks], acc[0][dt]);
          acc[1][dt] = MFMA16(vf, pb[1][ks], acc[1][dt]);
        }
      __builtin_amdgcn_s_setprio(0);
    }
  }

#pragma unroll
  for (int m = 0; m < 2; ++m) {
    const float inv = 1.0f / lrow[m];
    const size_t row = (size_t)b * T + wq + m * 16 + c16;
#pragma unroll
    for (int dt = 0; dt < 8; ++dt) {
      ushort4_ o = { f2bf(acc[m][dt][0] * inv), f2bf(acc[m][dt][1] * inv),
                     f2bf(acc[m][dt][2] * inv), f2bf(acc[m][dt][3] * inv) };
      *reinterpret_cast<ushort4_*>(ctx + row * C + h * D + dt * 16 + g * 4) = o;
    }
  }
}

// ---------------------------------------------------------------- launch
extern "C" void kernel_launch(void* const* d_in, const int* in_sizes, int n_in,
                              void* d_out, int out_size, void* d_ws, size_t ws_size,
                              hipStream_t stream) {
  const float* x  = (const float*)d_in[0];
  const float* Wq = (const float*)d_in[1];
  const float* bq = (const float*)d_in[2];
  const float* Wk = (const float*)d_in[3];
  const float* bk = (const float*)d_in[4];
  const float* Wv = (const float*)d_in[5];
  const float* bv = (const float*)d_in[6];
  const float* Wo = (const float*)d_in[7];
  const float* bo = (const float*)d_in[8];

  const int M = 8192, N = 2048, K = 2048;
  const size_t MB = 1u << 20;
  char* ws = (char*)d_ws;
  __hip_bfloat16* xb  = (__hip_bfloat16*)(ws);
  __hip_bfloat16* wqb = (__hip_bfloat16*)(ws + 32 * MB);
  __hip_bfloat16* wkb = (__hip_bfloat16*)(ws + 40 * MB);
  __hip_bfloat16* wvb = (__hip_bfloat16*)(ws + 48 * MB);
  __hip_bfloat16* wob = (__hip_bfloat16*)(ws + 56 * MB);
  __hip_bfloat16* Qb  = (__hip_bfloat16*)(ws + 64 * MB);
  __hip_bfloat16* Kb  = (__hip_bfloat16*)(ws + 96 * MB);
  __hip_bfloat16* Vtb = (__hip_bfloat16*)(ws + 128 * MB);
  if (ws_size < 160 * MB) return;

  cast5_f32_bf16<<<32768, 256, 0, stream>>>(x, Wq, Wk, Wv, Wo, xb, wqb, wkb, wvb, wob);

  const dim3 gg((M / 256) * (N / 256));
  gemm256p<0><<<gg, 512, 0, stream>>>(xb, wqb, bq, Qb, M, N, K);
  gemm256p<0><<<gg, 512, 0, stream>>>(xb, wkb, bk, Kb, M, N, K);
  gemm256p<1><<<gg, 512, 0, stream>>>(xb, wvb, bv, Vtb, M, N, K);

  attn_fwd12<<<64 * 16, 256, 0, stream>>>(Qb, Kb, Vtb, xb);

  gemm256p<2><<<gg, 512, 0, stream>>>(xb, wob, bo, d_out, M, N, K);
}

// Round 17
// 442.220 us; speedup vs baseline: 1.3112x; 1.0101x over previous
//
#include <hip/hip_runtime.h>
#include <hip/hip_bf16.h>
#include <cstdint>
#include <cstddef>

typedef __attribute__((ext_vector_type(8))) short short8;
typedef __attribute__((ext_vector_type(4))) short short4_;
typedef __attribute__((ext_vector_type(4))) float floatx4;
typedef __attribute__((ext_vector_type(4))) unsigned short ushort4_;

#define MFMA16(a, b, c) __builtin_amdgcn_mfma_f32_16x16x32_bf16((a), (b), (c), 0, 0, 0)

__device__ __forceinline__ unsigned short f2bf(float f) {
  __hip_bfloat16 h = __float2bfloat16(f);
  return *reinterpret_cast<unsigned short*>(&h);
}

__device__ __forceinline__ float exp2_fast(float x) {   // bare v_exp_f32 (exp2)
  float r;
  asm("v_exp_f32 %0, %1" : "=v"(r) : "v"(x));
  return r;
}

__device__ __forceinline__ void gl_lds16(const void* g, void* lds) {
  __builtin_amdgcn_global_load_lds(
      (const __attribute__((address_space(1))) void*)g,
      (__attribute__((address_space(3))) void*)lds, 16, 0, 0);
}

// ---------------------------------------------------------------- fused cast kernel
__global__ void cast5_f32_bf16(const float* __restrict__ x, const float* __restrict__ wq,
                               const float* __restrict__ wk, const float* __restrict__ wv,
                               const float* __restrict__ wo,
                               __hip_bfloat16* __restrict__ xb, __hip_bfloat16* __restrict__ wqb,
                               __hip_bfloat16* __restrict__ wkb, __hip_bfloat16* __restrict__ wvb,
                               __hip_bfloat16* __restrict__ wob) {
  const int bid = blockIdx.x;
  const float* src;
  __hip_bfloat16* dst;
  int base;
  if (bid < 16384)      { src = x;  dst = xb;  base = bid; }
  else if (bid < 20480) { src = wq; dst = wqb; base = bid - 16384; }
  else if (bid < 24576) { src = wk; dst = wkb; base = bid - 20480; }
  else if (bid < 28672) { src = wv; dst = wvb; base = bid - 24576; }
  else                  { src = wo; dst = wob; base = bid - 28672; }
  const int i = base * 1024 + threadIdx.x * 4;
  const float4 v = *reinterpret_cast<const float4*>(src + i);
  ushort4_ o = { f2bf(v.x), f2bf(v.y), f2bf(v.z), f2bf(v.w) };
  *reinterpret_cast<ushort4_*>(dst + i) = o;
}

// ---------------------------------------------------------------- GEMM v3: 256x256, BK=64, 4-phase
// 8 waves (2M x 4N), per-wave C 128x64 (acc 8x4 frags -> 128 AGPR).
// 2-slot LDS double buffer (128 KB, 1 block/CU). Per K-tile (64-deep): 4 phases
// (mh,kk) in order (0,0),(1,0),(0,1),(1,1): {reads (af 4 + bf 4 when kk changes)
// + staging burst (phases 0-1) -> barrier -> 16 MFMA -> barrier}.
// Ledger: prologue stages tile0 -> vmcnt(0)+barrier. Steady: tile kt stages kt+1
// into slot s^1 during phases 0-1 (8 gl_lds, >=2 phases slack); vmcnt(0) at tile
// end (only kt+1's loads outstanding) before the tile-final barrier. WAR: stage of
// kt+1 -> s^1 issues after tile kt-1's final barrier, by which its readers drained.
template <int MODE>
__global__ __launch_bounds__(512, 2)
void gemm256q(const __hip_bfloat16* __restrict__ Ap, const __hip_bfloat16* __restrict__ Bp,
              const float* __restrict__ bias, void* __restrict__ Cout,
              int M, int N, int K) {
  __shared__ __align__(16) __hip_bfloat16 SA[2][256 * 64];   // 2 x 32 KB
  __shared__ __align__(16) __hip_bfloat16 SB[2][256 * 64];   // 2 x 32 KB

  const int tid = threadIdx.x;
  const int wid = tid >> 6, lane = tid & 63;
  const int wr = wid >> 2, wc = wid & 3;
  const int g = lane >> 4, c16 = lane & 15;

  const int nbn = N >> 8;
  const int cpx = gridDim.x >> 3;
  const int swzb = (blockIdx.x & 7) * cpx + (blockIdx.x >> 3);
  const int bm = swzb / nbn, bn = swzb % nbn;

  // staging geometry: chunk = 8 rows x 64 cols = 1 KB per gl_lds
  const int srow8 = lane >> 3;            // row in chunk
  const int sc8 = lane & 7;               // phys 16B slot
  const int sgcol = (sc8 ^ srow8) * 8;    // pre-swizzled global col (elems); row&7==srow8

  floatx4 acc[8][4] = {};
  short8 af[4], bf[4];

  auto stageA = [&](int p, int kt, int slot) {
    const int ck = p * 8 + wid;                    // wave-uniform chunk 0..31
    const int row = ck * 8 + srow8;
    gl_lds16(Ap + (size_t)(bm * 256 + row) * K + kt * 64 + sgcol, SA[slot] + ck * 512);
  };
  auto stageB = [&](int p, int kt, int slot) {
    const int ck = p * 8 + wid;
    const int row = ck * 8 + srow8;
    gl_lds16(Bp + (size_t)(bn * 256 + row) * K + kt * 64 + sgcol, SB[slot] + ck * 512);
  };
  auto readA = [&](int slot, int mh, int kk) {
    const __hip_bfloat16* sa = SA[slot];
#pragma unroll
    for (int mi = 0; mi < 4; ++mi)
      af[mi] = *reinterpret_cast<const short8*>(
          sa + (wr * 128 + (mh * 4 + mi) * 16 + c16) * 64 + (((kk * 4 + g) ^ (c16 & 7)) * 8));
  };
  auto readB = [&](int slot, int kk) {
    const __hip_bfloat16* sb = SB[slot];
#pragma unroll
    for (int n = 0; n < 4; ++n)
      bf[n] = *reinterpret_cast<const short8*>(
          sb + (wc * 64 + n * 16 + c16) * 64 + (((kk * 4 + g) ^ (c16 & 7)) * 8));
  };
  auto mfma_q = [&](int mh) {
    __builtin_amdgcn_s_setprio(1);
#pragma unroll
    for (int mi = 0; mi < 4; ++mi)
#pragma unroll
      for (int n = 0; n < 4; ++n)
        acc[mh * 4 + mi][n] = MFMA16(af[mi], bf[n], acc[mh * 4 + mi][n]);
    __builtin_amdgcn_s_setprio(0);
  };

  const int nkt = K >> 6;                          // 32 K-tiles of 64
  // ---- prologue: stage tile 0 -> slot 0, full drain
#pragma unroll
  for (int p = 0; p < 4; ++p) { stageA(p, 0, 0); stageB(p, 0, 0); }
  asm volatile("s_waitcnt vmcnt(0)" ::: "memory");
  __builtin_amdgcn_s_barrier();

  for (int kt = 0; kt < nkt; ++kt) {
    const int s = kt & 1;
    const bool hn = (kt + 1 < nkt);
    // ---- phase 0: (mh0, kk0) + stage burst 1
    readA(s, 0, 0);
    readB(s, 0);
    if (hn) { stageA(0, kt + 1, s ^ 1); stageB(0, kt + 1, s ^ 1);
              stageA(1, kt + 1, s ^ 1); stageB(1, kt + 1, s ^ 1); }
    __builtin_amdgcn_s_barrier();
    mfma_q(0);
    __builtin_amdgcn_s_barrier();
    // ---- phase 1: (mh1, kk0) + stage burst 2
    readA(s, 1, 0);
    if (hn) { stageA(2, kt + 1, s ^ 1); stageB(2, kt + 1, s ^ 1);
              stageA(3, kt + 1, s ^ 1); stageB(3, kt + 1, s ^ 1); }
    __builtin_amdgcn_s_barrier();
    mfma_q(1);
    __builtin_amdgcn_s_barrier();
    // ---- phase 2: (mh0, kk1)
    readA(s, 0, 1);
    readB(s, 1);
    __builtin_amdgcn_s_barrier();
    mfma_q(0);
    __builtin_amdgcn_s_barrier();
    // ---- phase 3: (mh1, kk1) + tile drain
    readA(s, 1, 1);
    __builtin_amdgcn_s_barrier();
    mfma_q(1);
    if (hn) asm volatile("s_waitcnt vmcnt(0)" ::: "memory");  // kt+1's 8 loads: >=2 phases old
    __builtin_amdgcn_s_barrier();
  }

  // ---- epilogue (identical mapping to proven kernel)
#pragma unroll
  for (int n = 0; n < 4; ++n) {
    const int colg = bn * 256 + wc * 64 + n * 16 + c16;
    const float bv = bias[colg];
#pragma unroll
    for (int m = 0; m < 8; ++m) {
      const int rowg = bm * 256 + wr * 128 + m * 16 + g * 4;
      if (MODE == 0) {
        __hip_bfloat16* C = (__hip_bfloat16*)Cout;
#pragma unroll
        for (int j = 0; j < 4; ++j)
          C[(size_t)(rowg + j) * N + colg] = __float2bfloat16(acc[m][n][j] + bv);
      } else if (MODE == 1) {
        __hip_bfloat16* C = (__hip_bfloat16*)Cout;
        const int bb = rowg >> 11, t0 = rowg & 2047;
        ushort4_ pk = { f2bf(acc[m][n][0] + bv), f2bf(acc[m][n][1] + bv),
                        f2bf(acc[m][n][2] + bv), f2bf(acc[m][n][3] + bv) };
        *reinterpret_cast<ushort4_*>(C + ((size_t)bb * 2048 + colg) * 2048 + t0) = pk;
      } else {
        float* C = (float*)Cout;
#pragma unroll
        for (int j = 0; j < 4; ++j)
          C[(size_t)(rowg + j) * N + colg] = acc[m][n][j] + bv;
      }
    }
  }
}

// ---------------------------------------------------------------- flash attention v12 (causal)
// Proven round 16: 147 us. UNCHANGED.
__global__ __launch_bounds__(256, 2)
void attn_fwd12(const __hip_bfloat16* __restrict__ Q, const __hip_bfloat16* __restrict__ K,
                const __hip_bfloat16* __restrict__ Vt, __hip_bfloat16* __restrict__ ctx) {
  constexpr int T = 2048, C = 2048, D = 128;
  __shared__ __align__(16) __hip_bfloat16 Ks[64 * 128];
  __shared__ __align__(16) __hip_bfloat16 Vs[128 * 64];
  __shared__ __align__(16) __hip_bfloat16 Pl[4][16 * 64];

  const int tid = threadIdx.x;
  const int w = tid >> 6, lane = tid & 63;
  const int g = lane >> 4, c16 = lane & 15;

  const int bid = blockIdx.x;
  const int x = bid & 7;
  const int i = bid >> 3;
  const int lo = i & 3, hi = i >> 5;
  const int bh = x * 8 + ((i >> 2) & 7);
  const int qb = (int)((0xF12C4A97865B3DE0ull >> (4 * (hi * 4 + lo))) & 15);
  const int b = bh >> 4, h = bh & 15;
  const int wq = qb * 128 + w * 32;

  const __hip_bfloat16* Qh = Q + (size_t)b * T * C + h * D;
  const __hip_bfloat16* Kh = K + (size_t)b * T * C + h * D;
  const __hip_bfloat16* Vh = Vt + (size_t)bh * D * T;

  const float scale2 = 0.12751744f;   // (1/sqrt(128)) * log2(e)

  short8 qf[2][4];
#pragma unroll
  for (int m = 0; m < 2; ++m)
#pragma unroll
    for (int kk = 0; kk < 4; ++kk) {
      short8 v = *reinterpret_cast<const short8*>(Qh + (size_t)(wq + m * 16 + c16) * C + kk * 32 + g * 8);
      short8 r;
#pragma unroll
      for (int e = 0; e < 8; ++e) {
        unsigned short u = (unsigned short)v[e];
        __hip_bfloat16 bh16 = *reinterpret_cast<__hip_bfloat16*>(&u);
        r[e] = (short)f2bf(__bfloat162float(bh16) * scale2);
      }
      qf[m][kk] = r;
    }

  floatx4 acc[2][8] = {};
  float mrow[2] = {-INFINITY, -INFINITY};
  float lrow[2] = {0.f, 0.f};

  const int krow = tid >> 4;
  const int kslot = (tid & 15) ^ (krow & 7);
  const int kgcol = (tid & 15) * 8;
  const int vrow = tid >> 3;
  const int vslot = (tid & 7) ^ (vrow & 7);
  const int vgcol = (tid & 7) * 8;

  short8 kr[4], vr[4];
  auto gloadK = [&](int kb) {
#pragma unroll
    for (int p = 0; p < 4; ++p)
      kr[p] = *reinterpret_cast<const short8*>(Kh + (size_t)(kb + p * 16 + krow) * C + kgcol);
  };
  auto gloadV = [&](int kb) {
#pragma unroll
    for (int p = 0; p < 4; ++p)
      vr[p] = *reinterpret_cast<const short8*>(Vh + (size_t)(p * 32 + vrow) * T + kb + vgcol);
  };

  __hip_bfloat16* Pq = Pl[w];
  const int nkt = qb * 2 + 2;
  gloadK(0);
  gloadV(0);

  for (int kt = 0; kt < nkt; ++kt) {
    const int kb = kt * 64;
    __syncthreads();
#pragma unroll
    for (int p = 0; p < 4; ++p)
      *reinterpret_cast<short8*>(&Ks[(p * 16 + krow) * 128 + kslot * 8]) = kr[p];
#pragma unroll
    for (int p = 0; p < 4; ++p)
      *reinterpret_cast<short8*>(&Vs[(p * 32 + vrow) * 64 + vslot * 8]) = vr[p];
    __syncthreads();

    const bool hasnext = (kt + 1 < nkt);
    const bool part = (kb <= wq + 31);
    if (hasnext) gloadK(kb + 64);

    short8 pb[2][2];
    if (part) {
      floatx4 s[2][4] = {};
      __builtin_amdgcn_s_setprio(1);
#pragma unroll
      for (int n = 0; n < 4; ++n)
#pragma unroll
        for (int kk = 0; kk < 4; ++kk) {
          short8 kf = *reinterpret_cast<const short8*>(
              &Ks[(n * 16 + c16) * 128 + (((kk * 4 + g) ^ (c16 & 7)) * 8)]);
          s[0][n] = MFMA16(kf, qf[0][kk], s[0][n]);
          s[1][n] = MFMA16(kf, qf[1][kk], s[1][n]);
        }
      __builtin_amdgcn_s_setprio(0);

      const bool needmask = (kb + 63 > wq);
      float vmax[2];
      if (needmask) {
#pragma unroll
        for (int m = 0; m < 2; ++m) {
          const int q = wq + m * 16 + c16;
          float vm = -INFINITY;
#pragma unroll
          for (int n = 0; n < 4; ++n)
#pragma unroll
            for (int j = 0; j < 4; ++j) {
              float a = s[m][n][j];
              if (kb + n * 16 + g * 4 + j > q) a = -INFINITY;
              s[m][n][j] = a;
              vm = fmaxf(vm, a);
            }
          vmax[m] = vm;
        }
      } else {
#pragma unroll
        for (int m = 0; m < 2; ++m) {
          float v0 = fmaxf(fmaxf(s[m][0][0], s[m][0][1]), fmaxf(s[m][0][2], s[m][0][3]));
          float v1 = fmaxf(fmaxf(s[m][1][0], s[m][1][1]), fmaxf(s[m][1][2], s[m][1][3]));
          float v2 = fmaxf(fmaxf(s[m][2][0], s[m][2][1]), fmaxf(s[m][2][2], s[m][2][3]));
          float v3 = fmaxf(fmaxf(s[m][3][0], s[m][3][1]), fmaxf(s[m][3][2], s[m][3][3]));
          vmax[m] = fmaxf(fmaxf(v0, v1), fmaxf(v2, v3));
        }
      }
#pragma unroll
      for (int m = 0; m < 2; ++m) {
        vmax[m] = fmaxf(vmax[m], __shfl_xor(vmax[m], 16));
        vmax[m] = fmaxf(vmax[m], __shfl_xor(vmax[m], 32));
      }
      const float grow = fmaxf(vmax[0] - mrow[0], vmax[1] - mrow[1]);
      const bool nore = __all(grow <= 8.0f);
#pragma unroll
      for (int m = 0; m < 2; ++m) {
        const float mn = nore ? mrow[m] : fmaxf(mrow[m], vmax[m]);
        float rs = 0.f;
#pragma unroll
        for (int n = 0; n < 4; ++n) {
          float p0 = exp2_fast(s[m][n][0] - mn), p1 = exp2_fast(s[m][n][1] - mn);
          float p2 = exp2_fast(s[m][n][2] - mn), p3 = exp2_fast(s[m][n][3] - mn);
          rs += (p0 + p1) + (p2 + p3);
          ushort4_ pk = { f2bf(p0), f2bf(p1), f2bf(p2), f2bf(p3) };
          *reinterpret_cast<ushort4_*>(&Pq[c16 * 64 + (((4 * n + g) ^ c16) * 4)]) = pk;
        }
        rs += __shfl_xor(rs, 16);
        rs += __shfl_xor(rs, 32);
        if (nore) {
          lrow[m] += rs;
        } else {
          const float sc = exp2_fast(mrow[m] - mn);
          lrow[m] = lrow[m] * sc + rs;
          mrow[m] = mn;
#pragma unroll
          for (int dt = 0; dt < 8; ++dt)
#pragma unroll
            for (int j = 0; j < 4; ++j) acc[m][dt][j] *= sc;
        }
#pragma unroll
        for (int ks = 0; ks < 2; ++ks) {
          short4_ lo2 = *reinterpret_cast<const short4_*>(&Pq[c16 * 64 + (((8 * ks + 2 * g) ^ c16) * 4)]);
          short4_ hi2 = *reinterpret_cast<const short4_*>(&Pq[c16 * 64 + (((8 * ks + 2 * g + 1) ^ c16) * 4)]);
          short8 r;
          r[0] = lo2[0]; r[1] = lo2[1]; r[2] = lo2[2]; r[3] = lo2[3];
          r[4] = hi2[0]; r[5] = hi2[1]; r[6] = hi2[2]; r[7] = hi2[3];
          pb[m][ks] = r;
        }
      }
    }
    if (hasnext) gloadV(kb + 64);
    if (part) {
      __builtin_amdgcn_s_setprio(1);
#pragma unroll
      for (int dt = 0; dt < 8; ++dt)
#pragma unroll
        for (int ks = 0; ks < 2; ++ks) {
          const int pslot = ((ks * 4 + g) ^ (c16 & 7)) * 8;
          short8 vf = *reinterpret_cast<const short8*>(&Vs[(dt * 16 + c16) * 64 + pslot]);
          acc[0][dt] = MFMA16(vf, pb[0][ks], acc[0][dt]);
          acc[1][dt] = MFMA16(vf, pb[1][ks], acc[1][dt]);
        }
      __builtin_amdgcn_s_setprio(0);
    }
  }

#pragma unroll
  for (int m = 0; m < 2; ++m) {
    const float inv = 1.0f / lrow[m];
    const size_t row = (size_t)b * T + wq + m * 16 + c16;
#pragma unroll
    for (int dt = 0; dt < 8; ++dt) {
      ushort4_ o = { f2bf(acc[m][dt][0] * inv), f2bf(acc[m][dt][1] * inv),
                     f2bf(acc[m][dt][2] * inv), f2bf(acc[m][dt][3] * inv) };
      *reinterpret_cast<ushort4_*>(ctx + row * C + h * D + dt * 16 + g * 4) = o;
    }
  }
}

// ---------------------------------------------------------------- launch
extern "C" void kernel_launch(void* const* d_in, const int* in_sizes, int n_in,
                              void* d_out, int out_size, void* d_ws, size_t ws_size,
                              hipStream_t stream) {
  const float* x  = (const float*)d_in[0];
  const float* Wq = (const float*)d_in[1];
  const float* bq = (const float*)d_in[2];
  const float* Wk = (const float*)d_in[3];
  const float* bk = (const float*)d_in[4];
  const float* Wv = (const float*)d_in[5];
  const float* bv = (const float*)d_in[6];
  const float* Wo = (const float*)d_in[7];
  const float* bo = (const float*)d_in[8];

  const int M = 8192, N = 2048, K = 2048;
  const size_t MB = 1u << 20;
  char* ws = (char*)d_ws;
  __hip_bfloat16* xb  = (__hip_bfloat16*)(ws);
  __hip_bfloat16* wqb = (__hip_bfloat16*)(ws + 32 * MB);
  __hip_bfloat16* wkb = (__hip_bfloat16*)(ws + 40 * MB);
  __hip_bfloat16* wvb = (__hip_bfloat16*)(ws + 48 * MB);
  __hip_bfloat16* wob = (__hip_bfloat16*)(ws + 56 * MB);
  __hip_bfloat16* Qb  = (__hip_bfloat16*)(ws + 64 * MB);
  __hip_bfloat16* Kb  = (__hip_bfloat16*)(ws + 96 * MB);
  __hip_bfloat16* Vtb = (__hip_bfloat16*)(ws + 128 * MB);
  if (ws_size < 160 * MB) return;

  cast5_f32_bf16<<<32768, 256, 0, stream>>>(x, Wq, Wk, Wv, Wo, xb, wqb, wkb, wvb, wob);

  const dim3 gg((M / 256) * (N / 256));
  gemm256q<0><<<gg, 512, 0, stream>>>(xb, wqb, bq, Qb, M, N, K);
  gemm256q<0><<<gg, 512, 0, stream>>>(xb, wkb, bk, Kb, M, N, K);
  gemm256q<1><<<gg, 512, 0, stream>>>(xb, wvb, bv, Vtb, M, N, K);

  attn_fwd12<<<64 * 16, 256, 0, stream>>>(Qb, Kb, Vtb, xb);

  gemm256q<2><<<gg, 512, 0, stream>>>(xb, wob, bo, d_out, M, N, K);
}